// Round 16
// baseline (213.582 us; speedup 1.0000x reference)
//
#include <hip/hip_runtime.h>
#include <stdint.h>
#include <math.h>

#define N_ROWS 16384
#define D_DIM  4096
#define E_EXP  128
#define BM     64
#define BKR    128              // k per round
#define NR     (D_DIM / BKR)    // 32 rounds
#define NW     8                // waves per block
#define TAU    2.5e-4f

typedef short  short8 __attribute__((ext_vector_type(8)));
typedef float  f32x4  __attribute__((ext_vector_type(4)));

#define GAS __attribute__((address_space(1)))
#define LAS __attribute__((address_space(3)))

__device__ __forceinline__ void g2lds16(const float* g, uint8_t* l) {
  __builtin_amdgcn_global_load_lds((const GAS uint32_t*)g, (LAS uint32_t*)l, 16, 0, 0);
}

__device__ __forceinline__ uint32_t bf16_rne(float f) {
  uint32_t u = __builtin_bit_cast(uint32_t, f);
  return (u + 0x7fffu + ((u >> 16) & 1u)) >> 16;
}

// ---------------- kernel 0: split W into bf16 hi/lo, FRAGMENT-TILED (proven) --------
__global__ __launch_bounds__(256) void k0_split(const float* __restrict__ W,
                                                uint16_t* __restrict__ wt) {
  const int b  = blockIdx.x;
  const int t  = threadIdx.x;
  const int eg  = b >> 5;
  const int kcg = b & 31;
  const int kc  = kcg * 4 + (t >> 6);
  const int lane = t & 63;
  const int e  = eg * 16 + (lane & 15);
  const int k0 = kc * 32 + (lane >> 4) * 8;

  const float* src = W + (size_t)e * D_DIM + k0;
  f32x4 w0 = *(const f32x4*)src;
  f32x4 w1 = *(const f32x4*)(src + 4);
  float wf[8] = {w0[0], w0[1], w0[2], w0[3], w1[0], w1[1], w1[2], w1[3]};

  uint16_t h[8], l[8];
  #pragma unroll
  for (int j = 0; j < 8; ++j) {
    uint32_t hh = bf16_rne(wf[j]);
    float hf = __builtin_bit_cast(float, hh << 16);
    h[j] = (uint16_t)hh;
    l[j] = (uint16_t)bf16_rne(wf[j] - hf);
  }
  const size_t blkh = ((size_t)(eg * 128 + kc) * 2 + 0) * 512;
  const size_t blkl = ((size_t)(eg * 128 + kc) * 2 + 1) * 512;
  *(short8*)(wt + blkh + lane * 8) = *(const short8*)h;
  *(short8*)(wt + blkl + lane * 8) = *(const short8*)l;
}

// ---------------- kernel 1: barrier-free elastic-pipeline split-bf16 MFMA ----------
// 256 blocks (1/CU) x 8 waves; block = 64 rows x 128 experts, K=4096.
// x: gl_lds -> 3-deep raw FIFO; waves self-sync via LDS counters (no s_barrier).
__global__ __launch_bounds__(512) void k1_main(
    const float* __restrict__ x, const uint16_t* __restrict__ wt,
    const float* __restrict__ bias, float* __restrict__ out, int* __restrict__ flags)
{
  __shared__ __align__(16) uint8_t smem[3 * 32768 + 256];
  int* done   = (int*)(smem + 98304);        // [32]
  int* staged = done + 32;                   // [32]
  float* Ld = (float*)smem;                  // epilogue overlay [64][128]

  const int t    = threadIdx.x;
  const int lane = t & 63;
  const int wv   = __builtin_amdgcn_readfirstlane(t >> 6);
  const int rh   = wv >> 2;                  // row half 0/1
  const int eq   = wv & 3;                   // expert quarter
  const int row0 = blockIdx.x * BM;
  const int r15  = lane & 15, kg = lane >> 4;

  const short8* Wt8 = (const short8*)wt;

  // staging: tile = 2048 granules(16B); wave stages [wv*256, wv*256+256)
  auto stageTile = [&](int tile) {
    uint8_t* base = smem + (tile % 3) * 32768;
    #pragma unroll
    for (int i = 0; i < 4; ++i) {
      const int G  = wv * 256 + i * 64 + lane;
      const int rr = G >> 5, gp = G & 31;
      const int gs = gp ^ (rr & 7);
      const float* src = x + (size_t)(row0 + rr) * D_DIM + (size_t)tile * BKR + gs * 4;
      g2lds16(src, base + (size_t)G * 16);
    }
  };

  // ---- prologue: zero counters, stage tiles 0,1 ----
  if (t < 64) ((int*)(smem + 98304))[t] = 0;
  __syncthreads();
  stageTile(0);
  stageTile(1);
  asm volatile("s_waitcnt vmcnt(0)" ::: "memory");
  if (lane == 0) { atomicAdd(&staged[0], 1); atomicAdd(&staged[1], 1); }

  f32x4 acc[2][2] = {};   // [rg][egi]

  for (int r = 0; r < NR; ++r) {
    // A) wait tile r data ready (all waves' staging done)
    {
      volatile int* vs = (volatile int*)staged;
      while (vs[r] < NW) __builtin_amdgcn_s_sleep(2);
      asm volatile("" ::: "memory");
      __builtin_amdgcn_sched_barrier(0);
    }

    // B) stage tile r+2 (slot holds tile r-1; wait all waves consumed it)
    if (r + 2 < NR) {
      if (r >= 1) {
        volatile int* vd = (volatile int*)done;
        while (vd[r - 1] < NW) __builtin_amdgcn_s_sleep(2);
        asm volatile("" ::: "memory");
        __builtin_amdgcn_sched_barrier(0);
      }
      stageTile(r + 2);
    }

    // C) consume tile r: raw ds_read -> convert -> MFMA (wave-private, no barrier)
    const uint8_t* slot = smem + (r % 3) * 32768;
    #pragma unroll
    for (int s = 0; s < 4; ++s) {
      const int kcg = r * 4 + s;
      short8 bh[2], bl[2];
      #pragma unroll
      for (int egi = 0; egi < 2; ++egi) {
        const size_t bb = ((size_t)((eq * 2 + egi) * 128 + kcg) * 2) * 64 + lane;
        bh[egi] = Wt8[bb];
        bl[egi] = Wt8[bb + 64];
      }
      #pragma unroll
      for (int rg = 0; rg < 2; ++rg) {
        const int rr = rh * 32 + rg * 16 + r15;
        const int m  = rr & 7;
        const int g0 = s * 8 + kg * 2;
        f32x4 A = *(const f32x4*)(slot + ((size_t)rr * 32 + (g0 ^ m)) * 16);
        f32x4 B = *(const f32x4*)(slot + ((size_t)rr * 32 + ((g0 + 1) ^ m)) * 16);
        float xf[8] = {A[0], A[1], A[2], A[3], B[0], B[1], B[2], B[3]};
        uint32_t hpk[4], lpk[4];
        #pragma unroll
        for (int j = 0; j < 4; ++j) {
          uint32_t h0 = bf16_rne(xf[2*j]), h1 = bf16_rne(xf[2*j+1]);
          float h0f = __builtin_bit_cast(float, h0 << 16);
          float h1f = __builtin_bit_cast(float, h1 << 16);
          uint32_t l0 = bf16_rne(xf[2*j] - h0f), l1 = bf16_rne(xf[2*j+1] - h1f);
          hpk[j] = h0 | (h1 << 16);
          lpk[j] = l0 | (l1 << 16);
        }
        short8 ah = __builtin_bit_cast(short8, make_uint4(hpk[0], hpk[1], hpk[2], hpk[3]));
        short8 al = __builtin_bit_cast(short8, make_uint4(lpk[0], lpk[1], lpk[2], lpk[3]));
        #pragma unroll
        for (int egi = 0; egi < 2; ++egi) {
          acc[rg][egi] = __builtin_amdgcn_mfma_f32_16x16x32_bf16(ah, bh[egi], acc[rg][egi], 0, 0, 0);
          acc[rg][egi] = __builtin_amdgcn_mfma_f32_16x16x32_bf16(al, bh[egi], acc[rg][egi], 0, 0, 0);
          acc[rg][egi] = __builtin_amdgcn_mfma_f32_16x16x32_bf16(ah, bl[egi], acc[rg][egi], 0, 0, 0);
        }
      }
    }

    // D) mark: this wave done with tile r; its staging of r+2 complete
    asm volatile("s_waitcnt lgkmcnt(0)" ::: "memory");
    asm volatile("s_waitcnt vmcnt(0)" ::: "memory");
    if (lane == 0) {
      atomicAdd(&done[r], 1);
      if (r + 2 < NR) atomicAdd(&staged[r + 2], 1);
    }
  }

  // ---- epilogue: logits -> LDS [64][128], then top-3 ----
  __syncthreads();
  {
    float b0 = bias[eq * 32 + r15];
    float b1 = bias[eq * 32 + 16 + r15];
    #pragma unroll
    for (int rg = 0; rg < 2; ++rg)
      #pragma unroll
      for (int egi = 0; egi < 2; ++egi)
        #pragma unroll
        for (int i = 0; i < 4; ++i) {
          int rl = rh * 32 + rg * 16 + kg * 4 + i;
          int e  = (eq * 2 + egi) * 16 + r15;
          Ld[rl * 128 + e] = acc[rg][egi][i] + (egi ? b1 : b0);
        }
  }
  __syncthreads();

  // top-3 per row: 8 threads/row, 16 logits each, shfl merge
  {
    const int row = t >> 3, part = t & 7;
    float l1 = -3e38f, l2 = -3e38f, l3 = -3e38f;
    int   i1 = -1, i2 = -1, i3 = -1;
    auto ins = [&](float v, int e) {
      if (v > l1 || (v == l1 && e < i1)) { l3=l2; i3=i2; l2=l1; i2=i1; l1=v; i1=e; }
      else if (v > l2 || (v == l2 && e < i2)) { l3=l2; i3=i2; l2=v; i2=e; }
      else if (v > l3 || (v == l3 && e < i3)) { l3=v; i3=e; }
    };
    #pragma unroll
    for (int jj = 0; jj < 4; ++jj) {
      int j = (jj + t) & 3;
      const float* pp = Ld + row * 128 + part * 16 + j * 4;
      f32x4 v = *(const f32x4*)pp;
      int eb = part * 16 + j * 4;
      ins(v[0], eb); ins(v[1], eb + 1); ins(v[2], eb + 2); ins(v[3], eb + 3);
    }
    #pragma unroll
    for (int m = 1; m <= 4; m <<= 1) {
      float a1 = __shfl_xor(l1, m), a2 = __shfl_xor(l2, m), a3 = __shfl_xor(l3, m);
      int   b1i = __shfl_xor(i1, m), b2i = __shfl_xor(i2, m), b3i = __shfl_xor(i3, m);
      ins(a1, b1i); ins(a2, b2i); ins(a3, b3i);
    }
    if (part == 0) {
      int grow = row0 + row;
      int fl = ((l1 - l2) < TAU) || ((l2 - l3) < TAU);
      flags[grow] = fl;
      out[(size_t)grow * 2 + 0] = 1.f / (1.f + __expf(-l1));
      out[(size_t)grow * 2 + 1] = 1.f / (1.f + __expf(-l2));
      out[(size_t)N_ROWS * 2 + (size_t)grow * 2 + 0] = (float)i1;
      out[(size_t)N_ROWS * 2 + (size_t)grow * 2 + 1] = (float)i2;
    }
  }
}

// ---------------- kernel 2: exact f64 fixup for flagged rows (proven) ----------------
__global__ __launch_bounds__(1024) void k2_fix(
    const float* __restrict__ x, const float* __restrict__ W,
    const float* __restrict__ bias, const int* __restrict__ flags,
    float* __restrict__ out)
{
  __shared__ double lgs[E_EXP];
  const int t    = threadIdx.x;
  const int wvi  = t >> 6, lane = t & 63;
  const int e    = wvi * 8 + (lane >> 3);
  const int sub  = lane & 7;
  const int rbase = blockIdx.x * 8;

  for (int rr = 0; rr < 8; ++rr) {
    const int row = rbase + rr;
    if (!flags[row]) continue;
    const float* xr = x + (size_t)row * D_DIM;
    const float* wr = W + (size_t)e * D_DIM;
    double a0 = 0.0, a1 = 0.0, a2 = 0.0, a3 = 0.0;
    for (int j = 0; j < 128; ++j) {
      const int c4 = (j * 8 + sub) * 4;
      f32x4 xv = *(const f32x4*)(xr + c4);
      f32x4 wvv = *(const f32x4*)(wr + c4);
      a0 += (double)xv[0] * wvv[0];
      a1 += (double)xv[1] * wvv[1];
      a2 += (double)xv[2] * wvv[2];
      a3 += (double)xv[3] * wvv[3];
    }
    double acc = (a0 + a1) + (a2 + a3);
    #pragma unroll
    for (int m = 1; m <= 4; m <<= 1) acc += __shfl_xor(acc, m);
    if (sub == 0) lgs[e] = acc + (double)bias[e];
    __syncthreads();
    if (t == 0) {
      double l1 = -1e300, l2 = -1e300; int i1 = -1, i2 = -1;
      for (int ee = 0; ee < E_EXP; ++ee) {
        double v = lgs[ee];
        if (v > l1) { l2 = l1; i2 = i1; l1 = v; i1 = ee; }
        else if (v > l2) { l2 = v; i2 = ee; }
      }
      out[(size_t)row * 2 + 0] = (float)(1.0 / (1.0 + exp(-l1)));
      out[(size_t)row * 2 + 1] = (float)(1.0 / (1.0 + exp(-l2)));
      out[(size_t)N_ROWS * 2 + (size_t)row * 2 + 0] = (float)i1;
      out[(size_t)N_ROWS * 2 + (size_t)row * 2 + 1] = (float)i2;
    }
    __syncthreads();
  }
}

extern "C" void kernel_launch(void* const* d_in, const int* in_sizes, int n_in,
                              void* d_out, int out_size, void* d_ws, size_t ws_size,
                              hipStream_t stream) {
  const float* x  = (const float*)d_in[0];
  const float* Wm = (const float*)d_in[1];
  const float* b  = (const float*)d_in[2];
  float* out = (float*)d_out;

  uint16_t* wt = (uint16_t*)d_ws;                          // 2 MiB tiled W (h+l)
  int* flags = (int*)((uint8_t*)d_ws + 2u * 1024 * 1024);  // 64 KiB

  k0_split<<<dim3(256), dim3(256), 0, stream>>>(Wm, wt);
  k1_main<<<dim3(N_ROWS / BM), dim3(512), 0, stream>>>(x, wt, b, out, flags);
  k2_fix<<<dim3(N_ROWS / 8), dim3(1024), 0, stream>>>(x, Wm, b, flags, out);
}

// Round 17
// 185.870 us; speedup vs baseline: 1.1491x; 1.1491x over previous
//
#include <hip/hip_runtime.h>
#include <stdint.h>
#include <math.h>

#define N_ROWS 16384
#define D_DIM  4096
#define E_EXP  128
#define BM     64
#define BKR    128              // k per round
#define NR     (D_DIM / BKR)    // 32 rounds
#define NPROD  4
#define NCONS  4
#define TAU    2.5e-4f

typedef short  short8 __attribute__((ext_vector_type(8)));
typedef float  f32x4  __attribute__((ext_vector_type(4)));

__device__ __forceinline__ uint32_t bf16_rne(float f) {
  uint32_t u = __builtin_bit_cast(uint32_t, f);
  return (u + 0x7fffu + ((u >> 16) & 1u)) >> 16;
}

// ---------------- kernel 0: split W into bf16 hi/lo, FRAGMENT-TILED (proven) --------
__global__ __launch_bounds__(256) void k0_split(const float* __restrict__ W,
                                                uint16_t* __restrict__ wt) {
  const int b  = blockIdx.x;
  const int t  = threadIdx.x;
  const int eg  = b >> 5;
  const int kcg = b & 31;
  const int kc  = kcg * 4 + (t >> 6);
  const int lane = t & 63;
  const int e  = eg * 16 + (lane & 15);
  const int k0 = kc * 32 + (lane >> 4) * 8;

  const float* src = W + (size_t)e * D_DIM + k0;
  f32x4 w0 = *(const f32x4*)src;
  f32x4 w1 = *(const f32x4*)(src + 4);
  float wf[8] = {w0[0], w0[1], w0[2], w0[3], w1[0], w1[1], w1[2], w1[3]};

  uint16_t h[8], l[8];
  #pragma unroll
  for (int j = 0; j < 8; ++j) {
    uint32_t hh = bf16_rne(wf[j]);
    float hf = __builtin_bit_cast(float, hh << 16);
    h[j] = (uint16_t)hh;
    l[j] = (uint16_t)bf16_rne(wf[j] - hf);
  }
  const size_t blkh = ((size_t)(eg * 128 + kc) * 2 + 0) * 512;
  const size_t blkl = ((size_t)(eg * 128 + kc) * 2 + 1) * 512;
  *(short8*)(wt + blkh + lane * 8) = *(const short8*)h;
  *(short8*)(wt + blkl + lane * 8) = *(const short8*)l;
}

// ---------------- kernel 1: producer/consumer wave-specialized GEMM ----------------
// 256 blocks (1/CU) x 8 waves. Waves 0-3: producers (x load+convert+frag-write,
// 4-deep FIFO). Waves 4-7: consumers (frag-read + W + MFMA, 32 experts each).
__global__ __launch_bounds__(512) void k1_main(
    const float* __restrict__ x, const uint16_t* __restrict__ wt,
    const float* __restrict__ bias, float* __restrict__ out, int* __restrict__ flags)
{
  __shared__ __align__(16) uint8_t smem[4 * 32768 + 256];  // 4-slot frag FIFO + counters
  int* staged = (int*)(smem + 131072);   // [32]
  int* done   = staged + 32;             // [32]
  float* Ld   = (float*)smem;            // epilogue overlay [64][128]

  const int t    = threadIdx.x;
  const int lane = t & 63;
  const int wv   = __builtin_amdgcn_readfirstlane(t >> 6);
  const int row0 = blockIdx.x * BM;
  const int ggr  = lane >> 4, rrr = lane & 15;

  const short8* Wt8 = (const short8*)wt;

  if (t < 64) ((int*)(smem + 131072))[t] = 0;
  __syncthreads();

  f32x4 acc[4][2] = {};     // consumers: [rgg][egi]; producers: unused zeros

  if (wv < NPROD) {
    // ================= PRODUCER pw = wv : rows [pw*16, pw*16+16) =================
    const int pw  = wv;
    const int kch = lane & 15;          // k-chunk of 8 within 128
    const int rg4 = lane >> 4;          // sub-row group (4 rows)
    const float* xbase = x + (size_t)(row0 + pw * 16 + rg4 * 4) * D_DIM + kch * 8;
    const int s_w = kch >> 2, gg_w = kch & 3;

    f32x4 va[4][2], vb[4][2];
    #pragma unroll
    for (int i = 0; i < 4; ++i) {
      va[i][0] = *(const f32x4*)(xbase + (size_t)i * D_DIM);
      va[i][1] = *(const f32x4*)(xbase + (size_t)i * D_DIM + 4);
    }

    for (int r = 0; r < NR; ++r) {
      // issue loads for tile r+1 (in flight across the FIFO wait + convert)
      if (r + 1 < NR) {
        #pragma unroll
        for (int i = 0; i < 4; ++i) {
          const float* p = xbase + (size_t)i * D_DIM + (size_t)(r + 1) * BKR;
          vb[i][0] = *(const f32x4*)p;
          vb[i][1] = *(const f32x4*)(p + 4);
        }
      }
      // FIFO space: slot r%4 held tile r-4
      if (r >= 4) {
        volatile int* vd = (volatile int*)done;
        while (vd[r - 4] < NCONS) __builtin_amdgcn_s_sleep(2);
        asm volatile("" ::: "memory");
        __builtin_amdgcn_sched_barrier(0);
      }
      // convert + frag-write tile r
      uint8_t* slot = smem + (r & 3) * 32768;
      #pragma unroll
      for (int i = 0; i < 4; ++i) {
        float xf[8] = {va[i][0][0], va[i][0][1], va[i][0][2], va[i][0][3],
                       va[i][1][0], va[i][1][1], va[i][1][2], va[i][1][3]};
        uint32_t hpk[4], lpk[4];
        #pragma unroll
        for (int j = 0; j < 4; ++j) {
          uint32_t h0 = bf16_rne(xf[2*j]), h1 = bf16_rne(xf[2*j+1]);
          float h0f = __builtin_bit_cast(float, h0 << 16);
          float h1f = __builtin_bit_cast(float, h1 << 16);
          uint32_t l0 = bf16_rne(xf[2*j] - h0f), l1 = bf16_rne(xf[2*j+1] - h1f);
          hpk[j] = h0 | (h1 << 16);
          lpk[j] = l0 | (l1 << 16);
        }
        const int rr = rg4 * 4 + i;
        const int ps = gg_w * 16 + (rr ^ (gg_w << 1) ^ s_w);
        *(uint4*)(slot + (s_w * 8 + pw * 2 + 0) * 1024 + ps * 16) = make_uint4(hpk[0], hpk[1], hpk[2], hpk[3]);
        *(uint4*)(slot + (s_w * 8 + pw * 2 + 1) * 1024 + ps * 16) = make_uint4(lpk[0], lpk[1], lpk[2], lpk[3]);
      }
      asm volatile("s_waitcnt lgkmcnt(0)" ::: "memory");
      if (lane == 0) atomicAdd(&staged[r], 1);
      #pragma unroll
      for (int i = 0; i < 4; ++i) { va[i][0] = vb[i][0]; va[i][1] = vb[i][1]; }
    }
  } else {
    // ================= CONSUMER eq = wv-4 : experts [eq*32, eq*32+32) ============
    const int eq = wv - NPROD;
    const int p_r0 = ggr * 16 + (rrr ^ (ggr << 1));

    for (int r = 0; r < NR; ++r) {
      {
        volatile int* vs = (volatile int*)staged;
        while (vs[r] < NPROD) __builtin_amdgcn_s_sleep(2);
        asm volatile("" ::: "memory");
        __builtin_amdgcn_sched_barrier(0);
      }
      const uint8_t* slot = smem + (r & 3) * 32768;
      #pragma unroll
      for (int s = 0; s < 4; ++s) {
        const int pr = p_r0 ^ s;
        short8 A[4][2];
        #pragma unroll
        for (int rgg = 0; rgg < 4; ++rgg) {
          A[rgg][0] = *(const short8*)(slot + (s * 8 + rgg * 2 + 0) * 1024 + pr * 16);
          A[rgg][1] = *(const short8*)(slot + (s * 8 + rgg * 2 + 1) * 1024 + pr * 16);
        }
        const int kcg = r * 4 + s;
        #pragma unroll
        for (int egi = 0; egi < 2; ++egi) {
          const size_t bb = ((size_t)((eq * 2 + egi) * 128 + kcg) * 2) * 64 + lane;
          const short8 bh = Wt8[bb];
          const short8 bl = Wt8[bb + 64];
          #pragma unroll
          for (int rgg = 0; rgg < 4; ++rgg) {
            acc[rgg][egi] = __builtin_amdgcn_mfma_f32_16x16x32_bf16(A[rgg][0], bh, acc[rgg][egi], 0, 0, 0);
            acc[rgg][egi] = __builtin_amdgcn_mfma_f32_16x16x32_bf16(A[rgg][1], bh, acc[rgg][egi], 0, 0, 0);
            acc[rgg][egi] = __builtin_amdgcn_mfma_f32_16x16x32_bf16(A[rgg][0], bl, acc[rgg][egi], 0, 0, 0);
          }
        }
      }
      asm volatile("s_waitcnt lgkmcnt(0)" ::: "memory");
      if (lane == 0) atomicAdd(&done[r], 1);
    }
  }

  // ---- epilogue: consumers write logits+bias -> LDS overlay; all waves top-3 ----
  __syncthreads();
  if (wv >= NPROD) {
    const int eq = wv - NPROD;
    float bv[2] = {bias[(eq * 2 + 0) * 16 + rrr], bias[(eq * 2 + 1) * 16 + rrr]};
    #pragma unroll
    for (int rgg = 0; rgg < 4; ++rgg)
      #pragma unroll
      for (int egi = 0; egi < 2; ++egi)
        #pragma unroll
        for (int i = 0; i < 4; ++i) {
          int rl = rgg * 16 + ggr * 4 + i;
          int e  = (eq * 2 + egi) * 16 + rrr;
          Ld[rl * 128 + e] = acc[rgg][egi][i] + bv[egi];
        }
  }
  __syncthreads();

  // top-3 per row: 8 threads/row, 16 logits each, shfl merge (R16-proven)
  {
    const int row = t >> 3, part = t & 7;
    float l1 = -3e38f, l2 = -3e38f, l3 = -3e38f;
    int   i1 = -1, i2 = -1, i3 = -1;
    auto ins = [&](float v, int e) {
      if (v > l1 || (v == l1 && e < i1)) { l3=l2; i3=i2; l2=l1; i2=i1; l1=v; i1=e; }
      else if (v > l2 || (v == l2 && e < i2)) { l3=l2; i3=i2; l2=v; i2=e; }
      else if (v > l3 || (v == l3 && e < i3)) { l3=v; i3=e; }
    };
    #pragma unroll
    for (int jj = 0; jj < 4; ++jj) {
      int j = (jj + t) & 3;
      const float* pp = Ld + row * 128 + part * 16 + j * 4;
      f32x4 v = *(const f32x4*)pp;
      int eb = part * 16 + j * 4;
      ins(v[0], eb); ins(v[1], eb + 1); ins(v[2], eb + 2); ins(v[3], eb + 3);
    }
    #pragma unroll
    for (int m = 1; m <= 4; m <<= 1) {
      float a1 = __shfl_xor(l1, m), a2 = __shfl_xor(l2, m), a3 = __shfl_xor(l3, m);
      int   b1i = __shfl_xor(i1, m), b2i = __shfl_xor(i2, m), b3i = __shfl_xor(i3, m);
      ins(a1, b1i); ins(a2, b2i); ins(a3, b3i);
    }
    if (part == 0) {
      int grow = row0 + row;
      int fl = ((l1 - l2) < TAU) || ((l2 - l3) < TAU);
      flags[grow] = fl;
      out[(size_t)grow * 2 + 0] = 1.f / (1.f + __expf(-l1));
      out[(size_t)grow * 2 + 1] = 1.f / (1.f + __expf(-l2));
      out[(size_t)N_ROWS * 2 + (size_t)grow * 2 + 0] = (float)i1;
      out[(size_t)N_ROWS * 2 + (size_t)grow * 2 + 1] = (float)i2;
    }
  }
}

// ---------------- kernel 2: exact f64 fixup for flagged rows (proven) ----------------
__global__ __launch_bounds__(1024) void k2_fix(
    const float* __restrict__ x, const float* __restrict__ W,
    const float* __restrict__ bias, const int* __restrict__ flags,
    float* __restrict__ out)
{
  __shared__ double lgs[E_EXP];
  const int t    = threadIdx.x;
  const int wvi  = t >> 6, lane = t & 63;
  const int e    = wvi * 8 + (lane >> 3);
  const int sub  = lane & 7;
  const int rbase = blockIdx.x * 8;

  for (int rr = 0; rr < 8; ++rr) {
    const int row = rbase + rr;
    if (!flags[row]) continue;
    const float* xr = x + (size_t)row * D_DIM;
    const float* wr = W + (size_t)e * D_DIM;
    double a0 = 0.0, a1 = 0.0, a2 = 0.0, a3 = 0.0;
    for (int j = 0; j < 128; ++j) {
      const int c4 = (j * 8 + sub) * 4;
      f32x4 xv = *(const f32x4*)(xr + c4);
      f32x4 wvv = *(const f32x4*)(wr + c4);
      a0 += (double)xv[0] * wvv[0];
      a1 += (double)xv[1] * wvv[1];
      a2 += (double)xv[2] * wvv[2];
      a3 += (double)xv[3] * wvv[3];
    }
    double acc = (a0 + a1) + (a2 + a3);
    #pragma unroll
    for (int m = 1; m <= 4; m <<= 1) acc += __shfl_xor(acc, m);
    if (sub == 0) lgs[e] = acc + (double)bias[e];
    __syncthreads();
    if (t == 0) {
      double l1 = -1e300, l2 = -1e300; int i1 = -1, i2 = -1;
      for (int ee = 0; ee < E_EXP; ++ee) {
        double v = lgs[ee];
        if (v > l1) { l2 = l1; i2 = i1; l1 = v; i1 = ee; }
        else if (v > l2) { l2 = v; i2 = ee; }
      }
      out[(size_t)row * 2 + 0] = (float)(1.0 / (1.0 + exp(-l1)));
      out[(size_t)row * 2 + 1] = (float)(1.0 / (1.0 + exp(-l2)));
      out[(size_t)N_ROWS * 2 + (size_t)row * 2 + 0] = (float)i1;
      out[(size_t)N_ROWS * 2 + (size_t)row * 2 + 1] = (float)i2;
    }
    __syncthreads();
  }
}

extern "C" void kernel_launch(void* const* d_in, const int* in_sizes, int n_in,
                              void* d_out, int out_size, void* d_ws, size_t ws_size,
                              hipStream_t stream) {
  const float* x  = (const float*)d_in[0];
  const float* Wm = (const float*)d_in[1];
  const float* b  = (const float*)d_in[2];
  float* out = (float*)d_out;

  uint16_t* wt = (uint16_t*)d_ws;                          // 2 MiB tiled W (h+l)
  int* flags = (int*)((uint8_t*)d_ws + 2u * 1024 * 1024);  // 64 KiB

  k0_split<<<dim3(256), dim3(256), 0, stream>>>(Wm, wt);
  k1_main<<<dim3(N_ROWS / BM), dim3(512), 0, stream>>>(x, wt, b, out, flags);
  k2_fix<<<dim3(N_ROWS / 8), dim3(1024), 0, stream>>>(x, Wm, b, flags, out);
}

// Round 18
// 181.526 us; speedup vs baseline: 1.1766x; 1.0239x over previous
//
#include <hip/hip_runtime.h>
#include <stdint.h>
#include <math.h>

#define N_ROWS 16384
#define D_DIM  4096
#define E_EXP  128
#define BM     32
#define BKR    128              // k per round
#define NR     (D_DIM / BKR)    // 32 rounds
#define TAU    2.5e-4f

typedef short  short8 __attribute__((ext_vector_type(8)));
typedef float  f32x4  __attribute__((ext_vector_type(4)));

__device__ __forceinline__ uint32_t bf16_rne(float f) {
  uint32_t u = __builtin_bit_cast(uint32_t, f);
  return (u + 0x7fffu + ((u >> 16) & 1u)) >> 16;
}

// ---------------- kernel 0: split W into bf16 hi/lo, FRAGMENT-TILED ----------------
// blk = (eg*128 + kc)*2 + hl ; lane l: W[eg*16+(l&15)][kc*32+(l>>4)*8 ..+8]
// widened: 512 blocks x 128 threads (2 blocks/CU) to cut latency-bound tail.
__global__ __launch_bounds__(128) void k0_split(const float* __restrict__ W,
                                                uint16_t* __restrict__ wt) {
  const int b  = blockIdx.x;       // 0..511
  const int t  = threadIdx.x;      // 0..127
  const int eg  = b >> 6;          // 0..7
  const int kcg = b & 63;          // 0..63
  const int kc  = kcg * 2 + (t >> 6);   // 0..127
  const int lane = t & 63;
  const int e  = eg * 16 + (lane & 15);
  const int k0 = kc * 32 + (lane >> 4) * 8;

  const float* src = W + (size_t)e * D_DIM + k0;
  f32x4 w0 = *(const f32x4*)src;
  f32x4 w1 = *(const f32x4*)(src + 4);
  float wf[8] = {w0[0], w0[1], w0[2], w0[3], w1[0], w1[1], w1[2], w1[3]};

  uint16_t h[8], l[8];
  #pragma unroll
  for (int j = 0; j < 8; ++j) {
    uint32_t hh = bf16_rne(wf[j]);
    float hf = __builtin_bit_cast(float, hh << 16);
    h[j] = (uint16_t)hh;
    l[j] = (uint16_t)bf16_rne(wf[j] - hf);
  }
  const size_t blkh = ((size_t)(eg * 128 + kc) * 2 + 0) * 512;  // elements
  const size_t blkl = ((size_t)(eg * 128 + kc) * 2 + 1) * 512;
  *(short8*)(wt + blkh + lane * 8) = *(const short8*)h;
  *(short8*)(wt + blkl + lane * 8) = *(const short8*)l;
}

// ---------------- kernel 1: phase-pipelined split-bf16 MFMA GEMM + top3 + flags ----
// (byte-identical to the R12 run: best measured, 170.8 us total)
__global__ __launch_bounds__(512, 4) void k1_main(
    const float* __restrict__ x, const uint16_t* __restrict__ wt,
    const float* __restrict__ bias, float* __restrict__ out, int* __restrict__ flags)
{
  __shared__ __align__(16) uint8_t smem[32768];   // 2 x 16KB frag buffers
  float* Ld = (float*)smem;

  const int t    = threadIdx.x;
  const int lane = t & 63;
  const int wv   = __builtin_amdgcn_readfirstlane(t >> 6);
  const int row0 = blockIdx.x * BM;

  // ---- X staging map ----
  const int srow = t >> 4;        // 0..31
  const int skg  = t & 15;        // k-group of 8 within 128
  const float* xp = x + (size_t)(row0 + srow) * D_DIM + skg * 8;

  // ---- LDS write map ----
  const int s_w = skg >> 2, gg_w = skg & 3, rr_w = srow & 15, rg_w = srow >> 4;
  const int p_w  = gg_w * 16 + (rr_w ^ (gg_w << 1) ^ s_w);
  const int wa_h = (s_w * 4 + rg_w * 2 + 0) * 1024 + p_w * 16;
  const int wa_l = wa_h + 1024;

  // ---- LDS read map ----
  const int ggr = lane >> 4, rrr = lane & 15;
  const int p_r0 = ggr * 16 + (rrr ^ (ggr << 1));   // step s: slot = p_r0 ^ s

  // ---- W tiled fragment pointer ----
  const short8* Wt8 = (const short8*)wt;
  const int ccol = lane & 15;

  f32x4 acc[2] = {};

  // ---- prologue: tile 0 convert -> buf0; xa=tile1, xb=tile2, xc=tile3; Wc=W(0) ----
  {
    f32x4 t0 = *((const f32x4*)xp + 0), t1 = *((const f32x4*)xp + 1);
    float xf[8] = {t0[0], t0[1], t0[2], t0[3], t1[0], t1[1], t1[2], t1[3]};
    uint32_t hpk[4], lpk[4];
    #pragma unroll
    for (int j = 0; j < 4; ++j) {
      uint32_t h0 = bf16_rne(xf[2*j]), h1 = bf16_rne(xf[2*j+1]);
      float h0f = __builtin_bit_cast(float, h0 << 16);
      float h1f = __builtin_bit_cast(float, h1 << 16);
      uint32_t l0 = bf16_rne(xf[2*j] - h0f), l1 = bf16_rne(xf[2*j+1] - h1f);
      hpk[j] = h0 | (h1 << 16);
      lpk[j] = l0 | (l1 << 16);
    }
    *(uint4*)(smem + wa_h) = make_uint4(hpk[0], hpk[1], hpk[2], hpk[3]);
    *(uint4*)(smem + wa_l) = make_uint4(lpk[0], lpk[1], lpk[2], lpk[3]);
  }
  f32x4 xa0, xa1, xb0, xb1, xc0, xc1;
  xa0 = *((const f32x4*)(xp + 1 * BKR) + 0); xa1 = *((const f32x4*)(xp + 1 * BKR) + 1);
  xb0 = *((const f32x4*)(xp + 2 * BKR) + 0); xb1 = *((const f32x4*)(xp + 2 * BKR) + 1);
  xc0 = *((const f32x4*)(xp + 3 * BKR) + 0); xc1 = *((const f32x4*)(xp + 3 * BKR) + 1);

  short8 Wc[8], Wn[8];
  {
    const size_t b0 = ((size_t)(wv * 128) * 2) * 64 + lane;
    #pragma unroll
    for (int q = 0; q < 8; ++q) Wc[q] = Wt8[b0 + (size_t)q * 64];
  }
  asm volatile("s_waitcnt lgkmcnt(0)" ::: "memory");
  __builtin_amdgcn_s_barrier();

  #pragma unroll 2
  for (int r = 0; r < NR; ++r) {
    uint8_t* rbuf = smem + (r & 1) * 16384;          // MFMA reads tile r here
    uint8_t* wbuf = smem + ((r + 1) & 1) * 16384;    // convert writes tile r+1 here

    // 1) issue W(r+1)
    if (r + 1 < NR) {
      const size_t nb = ((size_t)(wv * 128 + (r + 1) * 4) * 2) * 64 + lane;
      #pragma unroll
      for (int q = 0; q < 8; ++q) Wn[q] = Wt8[nb + (size_t)q * 64];
    }

    // 2) convert xa (tile r+1) -> regs (VALU fills MFMA-phase latency shadows)
    uint32_t hpk[4], lpk[4];
    if (r + 1 < NR) {
      float xf[8] = {xa0[0], xa0[1], xa0[2], xa0[3], xa1[0], xa1[1], xa1[2], xa1[3]};
      #pragma unroll
      for (int j = 0; j < 4; ++j) {
        uint32_t h0 = bf16_rne(xf[2*j]), h1 = bf16_rne(xf[2*j+1]);
        float h0f = __builtin_bit_cast(float, h0 << 16);
        float h1f = __builtin_bit_cast(float, h1 << 16);
        uint32_t l0 = bf16_rne(xf[2*j] - h0f), l1 = bf16_rne(xf[2*j+1] - h1f);
        hpk[j] = h0 | (h1 << 16);
        lpk[j] = l0 | (l1 << 16);
      }
    }

    // 3) MFMA round r from rbuf + Wc
    #pragma unroll
    for (int s = 0; s < 4; ++s) {
      const int pr = p_r0 ^ s;
      const short8 bh = Wc[s * 2 + 0], bl = Wc[s * 2 + 1];
      #pragma unroll
      for (int rg = 0; rg < 2; ++rg) {
        const uint8_t* fb = rbuf + (s * 4 + rg * 2) * 1024 + pr * 16;
        short8 ah = *(const short8*)fb;
        short8 al = *(const short8*)(fb + 1024);
        acc[rg] = __builtin_amdgcn_mfma_f32_16x16x32_bf16(ah, bh, acc[rg], 0, 0, 0);
        acc[rg] = __builtin_amdgcn_mfma_f32_16x16x32_bf16(al, bh, acc[rg], 0, 0, 0);
        acc[rg] = __builtin_amdgcn_mfma_f32_16x16x32_bf16(ah, bl, acc[rg], 0, 0, 0);
      }
    }

    // 4) store tile r+1 frags into the other buffer (no intra-round hazard)
    if (r + 1 < NR) {
      *(uint4*)(wbuf + wa_h) = make_uint4(hpk[0], hpk[1], hpk[2], hpk[3]);
      *(uint4*)(wbuf + wa_l) = make_uint4(lpk[0], lpk[1], lpk[2], lpk[3]);
    }

    // 5) rotate x pipeline; issue tile r+4
    xa0 = xb0; xa1 = xb1; xb0 = xc0; xb1 = xc1;
    if (r + 4 < NR) {
      const f32x4* np = (const f32x4*)(xp + (size_t)(r + 4) * BKR);
      xc0 = np[0]; xc1 = np[1];
    }

    // 6) one barrier per round
    asm volatile("s_waitcnt lgkmcnt(0)" ::: "memory");
    __builtin_amdgcn_s_barrier();

    // 7) rotate W
    #pragma unroll
    for (int q = 0; q < 8; ++q) Wc[q] = Wn[q];
  }

  // ---- epilogue: logits -> LDS [32][128] ----
  float b0 = bias[wv * 16 + ccol];
  __syncthreads();
  #pragma unroll
  for (int rg = 0; rg < 2; ++rg)
    #pragma unroll
    for (int i = 0; i < 4; ++i) {
      int row = rg * 16 + ggr * 4 + i;
      int e = wv * 16 + ccol;
      Ld[row * 128 + e] = acc[rg][i] + b0;
    }
  __syncthreads();

  // ---- top-3 per row: 16 threads/row, 8 logits each, shfl merge ----
  {
    const int row = t >> 4, part = t & 15;
    float l1 = -3e38f, l2 = -3e38f, l3 = -3e38f;
    int   i1 = -1, i2 = -1, i3 = -1;
    auto ins = [&](float v, int e) {
      if (v > l1 || (v == l1 && e < i1)) { l3=l2; i3=i2; l2=l1; i2=i1; l1=v; i1=e; }
      else if (v > l2 || (v == l2 && e < i2)) { l3=l2; i3=i2; l2=v; i2=e; }
      else if (v > l3 || (v == l3 && e < i3)) { l3=v; i3=e; }
    };
    #pragma unroll
    for (int j = 0; j < 2; ++j) {
      const float* pp = Ld + row * 128 + part * 8 + j * 4;
      f32x4 v = *(const f32x4*)pp;
      int eb = part * 8 + j * 4;
      ins(v[0], eb); ins(v[1], eb + 1); ins(v[2], eb + 2); ins(v[3], eb + 3);
    }
    #pragma unroll
    for (int m = 1; m <= 8; m <<= 1) {
      float a1 = __shfl_xor(l1, m), a2 = __shfl_xor(l2, m), a3 = __shfl_xor(l3, m);
      int   b1i = __shfl_xor(i1, m), b2i = __shfl_xor(i2, m), b3i = __shfl_xor(i3, m);
      ins(a1, b1i); ins(a2, b2i); ins(a3, b3i);
    }
    if (part == 0) {
      int grow = row0 + row;
      int fl = ((l1 - l2) < TAU) || ((l2 - l3) < TAU);
      flags[grow] = fl;
      out[(size_t)grow * 2 + 0] = 1.f / (1.f + __expf(-l1));
      out[(size_t)grow * 2 + 1] = 1.f / (1.f + __expf(-l2));
      out[(size_t)N_ROWS * 2 + (size_t)grow * 2 + 0] = (float)i1;
      out[(size_t)N_ROWS * 2 + (size_t)grow * 2 + 1] = (float)i2;
    }
  }
}

// ---------------- kernel 2: exact f64 fixup for flagged rows (proven) ----------------
__global__ __launch_bounds__(1024) void k2_fix(
    const float* __restrict__ x, const float* __restrict__ W,
    const float* __restrict__ bias, const int* __restrict__ flags,
    float* __restrict__ out)
{
  __shared__ double lgs[E_EXP];
  const int t    = threadIdx.x;        // 1024 threads = 16 waves
  const int wvi  = t >> 6, lane = t & 63;
  const int e    = wvi * 8 + (lane >> 3);
  const int sub  = lane & 7;
  const int rbase = blockIdx.x * 8;

  for (int rr = 0; rr < 8; ++rr) {
    const int row = rbase + rr;
    if (!flags[row]) continue;
    const float* xr = x + (size_t)row * D_DIM;
    const float* wr = W + (size_t)e * D_DIM;
    double a0 = 0.0, a1 = 0.0, a2 = 0.0, a3 = 0.0;
    for (int j = 0; j < 128; ++j) {
      const int c4 = (j * 8 + sub) * 4;
      f32x4 xv = *(const f32x4*)(xr + c4);
      f32x4 wvv = *(const f32x4*)(wr + c4);
      a0 += (double)xv[0] * wvv[0];
      a1 += (double)xv[1] * wvv[1];
      a2 += (double)xv[2] * wvv[2];
      a3 += (double)xv[3] * wvv[3];
    }
    double acc = (a0 + a1) + (a2 + a3);
    #pragma unroll
    for (int m = 1; m <= 4; m <<= 1) acc += __shfl_xor(acc, m);
    if (sub == 0) lgs[e] = acc + (double)bias[e];
    __syncthreads();
    if (t == 0) {
      double l1 = -1e300, l2 = -1e300; int i1 = -1, i2 = -1;
      for (int ee = 0; ee < E_EXP; ++ee) {
        double v = lgs[ee];
        if (v > l1) { l2 = l1; i2 = i1; l1 = v; i1 = ee; }
        else if (v > l2) { l2 = v; i2 = ee; }
      }
      out[(size_t)row * 2 + 0] = (float)(1.0 / (1.0 + exp(-l1)));
      out[(size_t)row * 2 + 1] = (float)(1.0 / (1.0 + exp(-l2)));
      out[(size_t)N_ROWS * 2 + (size_t)row * 2 + 0] = (float)i1;
      out[(size_t)N_ROWS * 2 + (size_t)row * 2 + 1] = (float)i2;
    }
    __syncthreads();
  }
}

extern "C" void kernel_launch(void* const* d_in, const int* in_sizes, int n_in,
                              void* d_out, int out_size, void* d_ws, size_t ws_size,
                              hipStream_t stream) {
  const float* x  = (const float*)d_in[0];
  const float* Wm = (const float*)d_in[1];
  const float* b  = (const float*)d_in[2];
  float* out = (float*)d_out;

  uint16_t* wt = (uint16_t*)d_ws;                          // 2 MiB tiled W (h+l)
  int* flags = (int*)((uint8_t*)d_ws + 2u * 1024 * 1024);  // 64 KiB

  k0_split<<<dim3(512), dim3(128), 0, stream>>>(Wm, wt);
  k1_main<<<dim3(N_ROWS / BM), dim3(512), 0, stream>>>(x, wt, b, out, flags);
  k2_fix<<<dim3(N_ROWS / 8), dim3(1024), 0, stream>>>(x, Wm, b, flags, out);
}